// Round 1
// baseline (656.980 us; speedup 1.0000x reference)
//
#include <hip/hip_runtime.h>
#include <hip/hip_bf16.h>
#include <cstddef>

#define N_NODES 50000
#define N_EDGES 400000
#define TOT_EDGES (N_EDGES + N_NODES)

// ---------------------------------------------------------------------------
// CSR build
// ---------------------------------------------------------------------------
__global__ void zero_int(int* __restrict__ p, int n) {
  int i = blockIdx.x * blockDim.x + threadIdx.x;
  if (i < n) p[i] = 0;
}

__global__ void count_kernel(const int* __restrict__ ei, int* __restrict__ cnt) {
  int e = blockIdx.x * blockDim.x + threadIdx.x;
  if (e >= TOT_EDGES) return;
  int dst = (e < N_EDGES) ? ei[N_EDGES + e] : (e - N_EDGES);
  atomicAdd(&cnt[dst], 1);
}

// single-block exclusive scan over n counts -> rowstart[0..n], cursor=rowstart
__global__ void scan_kernel(const int* __restrict__ cnt, int* __restrict__ rowstart,
                            int* __restrict__ cursor, int n) {
  __shared__ int wsum[4];
  __shared__ int carry_s;
  const int t = threadIdx.x;
  const int lane = t & 63;
  const int w = t >> 6;
  if (t == 0) carry_s = 0;
  __syncthreads();
  for (int base = 0; base < n; base += 256) {
    const int i = base + t;
    int v = (i < n) ? cnt[i] : 0;
    int x = v;
#pragma unroll
    for (int off = 1; off < 64; off <<= 1) {
      int y = __shfl_up(x, off);
      if (lane >= off) x += y;
    }
    if (lane == 63) wsum[w] = x;
    __syncthreads();
    int woff = 0;
    for (int j = 0; j < w; ++j) woff += wsum[j];
    const int incl = x + woff + carry_s;
    if (i < n) {
      rowstart[i] = incl - v;
      cursor[i]   = incl - v;
    }
    __syncthreads();
    if (t == 0) carry_s += wsum[0] + wsum[1] + wsum[2] + wsum[3];
    __syncthreads();
  }
  if (t == 0) rowstart[n] = carry_s;
}

__global__ void fill_kernel(const int* __restrict__ ei, int* __restrict__ cursor,
                            int* __restrict__ csr_src) {
  int e = blockIdx.x * blockDim.x + threadIdx.x;
  if (e >= TOT_EDGES) return;
  int s, d;
  if (e < N_EDGES) { s = ei[e]; d = ei[N_EDGES + e]; }
  else             { s = d = e - N_EDGES; }
  int pos = atomicAdd(&cursor[d], 1);
  csr_src[pos] = s;
}

// ---------------------------------------------------------------------------
// f32 tiled GEMM: C[M,N] = A[M,K] @ B[K,N].  N,K multiples of 64; M guarded.
// block 256 threads, 64x64 tile, 4x4 per thread.
// ---------------------------------------------------------------------------
template <int BM, int BN, int BK>
__global__ __launch_bounds__(256) void gemm_f32(const float* __restrict__ A,
                                                const float* __restrict__ B,
                                                float* __restrict__ C,
                                                int M, int N, int K) {
  __shared__ float Ast[BK][BM + 4];  // transposed A tile
  __shared__ float Bs[BK][BN + 4];
  const int tid = threadIdx.x;
  const int tx = tid & 15, ty = tid >> 4;
  const int bm = blockIdx.x * BM, bn = blockIdx.y * BN;
  float acc[4][4] = {};
  for (int k0 = 0; k0 < K; k0 += BK) {
#pragma unroll
    for (int i = 0; i < BM * BK / 1024; ++i) {
      int idx = (i * 256 + tid) * 4;
      int r = idx / BK, c = idx % BK;  // r = m, c = k
      float4 v = make_float4(0.f, 0.f, 0.f, 0.f);
      if (bm + r < M) v = *(const float4*)&A[(size_t)(bm + r) * K + k0 + c];
      Ast[c + 0][r] = v.x; Ast[c + 1][r] = v.y;
      Ast[c + 2][r] = v.z; Ast[c + 3][r] = v.w;
    }
#pragma unroll
    for (int i = 0; i < BK * BN / 1024; ++i) {
      int idx = (i * 256 + tid) * 4;
      int r = idx / BN, c = idx % BN;  // r = k, c = n
      float4 v = *(const float4*)&B[(size_t)(k0 + r) * N + bn + c];
      *(float4*)&Bs[r][c] = v;
    }
    __syncthreads();
#pragma unroll
    for (int k = 0; k < BK; ++k) {
      float4 a = *(const float4*)&Ast[k][ty * 4];
      float4 b = *(const float4*)&Bs[k][tx * 4];
      acc[0][0] += a.x * b.x; acc[0][1] += a.x * b.y; acc[0][2] += a.x * b.z; acc[0][3] += a.x * b.w;
      acc[1][0] += a.y * b.x; acc[1][1] += a.y * b.y; acc[1][2] += a.y * b.z; acc[1][3] += a.y * b.w;
      acc[2][0] += a.z * b.x; acc[2][1] += a.z * b.y; acc[2][2] += a.z * b.z; acc[2][3] += a.z * b.w;
      acc[3][0] += a.w * b.x; acc[3][1] += a.w * b.y; acc[3][2] += a.w * b.z; acc[3][3] += a.w * b.w;
    }
    __syncthreads();
  }
#pragma unroll
  for (int i = 0; i < 4; ++i) {
    int gr = bm + ty * 4 + i;
    if (gr < M) {
      float4 v = make_float4(acc[i][0], acc[i][1], acc[i][2], acc[i][3]);
      *(float4*)&C[(size_t)gr * N + bn + tx * 4] = v;
    }
  }
}

// ---------------------------------------------------------------------------
// per-node attention coefficients: a_src[n][h] = <h[n,h,:], att_src[h,:]>
// one wave per node
// ---------------------------------------------------------------------------
template <int H, int D>
__global__ __launch_bounds__(256) void att_kernel(const float* __restrict__ h,
                                                  const float* __restrict__ att_s,
                                                  const float* __restrict__ att_d,
                                                  float* __restrict__ a_s,
                                                  float* __restrict__ a_d, int n) {
  const int wid = (blockIdx.x * blockDim.x + threadIdx.x) >> 6;
  const int lane = threadIdx.x & 63;
  if (wid >= n) return;
  constexpr int R = H * D / 64;  // floats per lane
  const float* row = h + (size_t)wid * H * D + lane * R;
  const float* asv = att_s + lane * R;
  const float* adv = att_d + lane * R;
  float ps = 0.f, pd = 0.f;
#pragma unroll
  for (int j = 0; j < R; ++j) {
    float v = row[j];
    ps += v * asv[j];
    pd += v * adv[j];
  }
  constexpr int G = D / R;  // lanes per head
#pragma unroll
  for (int off = 1; off < G; off <<= 1) {
    ps += __shfl_xor(ps, off);
    pd += __shfl_xor(pd, off);
  }
  if ((lane & (G - 1)) == 0) {
    int hd = lane / G;
    a_s[(size_t)wid * H + hd] = ps;
    a_d[(size_t)wid * H + hd] = pd;
  }
}

// ---------------------------------------------------------------------------
// per-dst aggregation with segment softmax; one wave per dst node
// ---------------------------------------------------------------------------
template <int H, int D, bool DO_ELU>
__global__ __launch_bounds__(256) void aggregate_kernel(
    const float* __restrict__ hsrc, const float* __restrict__ a_src,
    const float* __restrict__ a_dst, const int* __restrict__ rowstart,
    const int* __restrict__ csr_src, const float* __restrict__ bias,
    float* __restrict__ out, int n) {
  const int wid = (blockIdx.x * blockDim.x + threadIdx.x) >> 6;
  const int lane = threadIdx.x & 63;
  if (wid >= n) return;
  const int rs = rowstart[wid], re = rowstart[wid + 1];

  float adn[H];
#pragma unroll
  for (int h = 0; h < H; ++h) adn[h] = a_dst[(size_t)wid * H + h];

  // phase A: per-head max over incoming edges
  float mx[H];
#pragma unroll
  for (int h = 0; h < H; ++h) mx[h] = -1e30f;
  for (int k = rs + lane; k < re; k += 64) {
    const int s = csr_src[k];
    if constexpr (H == 4) {
      float4 av = *(const float4*)&a_src[(size_t)s * 4];
      float ev[4] = {av.x, av.y, av.z, av.w};
#pragma unroll
      for (int h = 0; h < 4; ++h) {
        float e = ev[h] + adn[h];
        e = (e > 0.f) ? e : 0.2f * e;
        mx[h] = fmaxf(mx[h], e);
      }
    } else {
      float e = a_src[s] + adn[0];
      e = (e > 0.f) ? e : 0.2f * e;
      mx[0] = fmaxf(mx[0], e);
    }
  }
#pragma unroll
  for (int h = 0; h < H; ++h)
    for (int off = 32; off; off >>= 1) mx[h] = fmaxf(mx[h], __shfl_xor(mx[h], off));

  // phase B: sum of exp
  float sm[H] = {};
  for (int k = rs + lane; k < re; k += 64) {
    const int s = csr_src[k];
    if constexpr (H == 4) {
      float4 av = *(const float4*)&a_src[(size_t)s * 4];
      float ev[4] = {av.x, av.y, av.z, av.w};
#pragma unroll
      for (int h = 0; h < 4; ++h) {
        float e = ev[h] + adn[h];
        e = (e > 0.f) ? e : 0.2f * e;
        sm[h] += __expf(e - mx[h]);
      }
    } else {
      float e = a_src[s] + adn[0];
      e = (e > 0.f) ? e : 0.2f * e;
      sm[0] += __expf(e - mx[0]);
    }
  }
#pragma unroll
  for (int h = 0; h < H; ++h) {
    for (int off = 32; off; off >>= 1) sm[h] += __shfl_xor(sm[h], off);
    sm[h] = 1.f / (sm[h] + 1e-16f);
  }

  // phase C: weighted accumulate of h[src]
  constexpr int R = H * D / 64;  // output floats per lane
  const int col0 = lane * R;
  const int hd = col0 / D;
  float acc[R] = {};
  for (int k = rs; k < re; ++k) {
    const int s = csr_src[k];
    float e = a_src[(size_t)s * H + hd] + adn[hd];
    e = (e > 0.f) ? e : 0.2f * e;
    const float alpha = __expf(e - mx[hd]) * sm[hd];
    const float* hr = hsrc + (size_t)s * (H * D) + col0;
    if constexpr (R >= 4) {
#pragma unroll
      for (int j = 0; j < R; j += 4) {
        float4 v = *(const float4*)(hr + j);
        acc[j + 0] += alpha * v.x;
        acc[j + 1] += alpha * v.y;
        acc[j + 2] += alpha * v.z;
        acc[j + 3] += alpha * v.w;
      }
    } else {
      float2 v = *(const float2*)hr;
      acc[0] += alpha * v.x;
      acc[1] += alpha * v.y;
    }
  }

  float* orow = out + (size_t)wid * (H * D) + col0;
#pragma unroll
  for (int j = 0; j < R; ++j) {
    float v = acc[j] + bias[col0 + j];
    if (DO_ELU) v = (v > 0.f) ? v : (__expf(v) - 1.f);
    orow[j] = v;
  }
}

// ---------------------------------------------------------------------------
// row L2-normalize (D=128), in place; one wave per node
// ---------------------------------------------------------------------------
__global__ __launch_bounds__(256) void normalize_kernel(float* __restrict__ z, int n) {
  const int wid = (blockIdx.x * blockDim.x + threadIdx.x) >> 6;
  const int lane = threadIdx.x & 63;
  if (wid >= n) return;
  float* p = z + (size_t)wid * 128 + lane * 2;
  float2 v = *(float2*)p;
  float s = v.x * v.x + v.y * v.y;
#pragma unroll
  for (int off = 32; off; off >>= 1) s += __shfl_xor(s, off);
  float nrm = fmaxf(sqrtf(s), 1e-12f);
  float inv = 1.f / nrm;
  v.x *= inv;
  v.y *= inv;
  *(float2*)p = v;
}

// ---------------------------------------------------------------------------
extern "C" void kernel_launch(void* const* d_in, const int* in_sizes, int n_in,
                              void* d_out, int out_size, void* d_ws, size_t ws_size,
                              hipStream_t stream) {
  const float* x        = (const float*)d_in[0];
  const int*   ei       = (const int*)d_in[1];
  const float* W1       = (const float*)d_in[2];
  const float* att_src1 = (const float*)d_in[3];
  const float* att_dst1 = (const float*)d_in[4];
  const float* bias1    = (const float*)d_in[5];
  const float* W2       = (const float*)d_in[6];
  const float* att_src2 = (const float*)d_in[7];
  const float* att_dst2 = (const float*)d_in[8];
  const float* bias2    = (const float*)d_in[9];
  float* out = (float*)d_out;

  constexpr int N_ = N_NODES;
  char* ws = (char*)d_ws;
  size_t off = 0;
  auto alloc = [&](size_t bytes) {
    char* p = ws + off;
    off = (off + bytes + 255) & ~(size_t)255;
    return p;
  };
  float* h1   = (float*)alloc(sizeof(float) * (size_t)N_ * 512);
  float* out1 = (float*)alloc(sizeof(float) * (size_t)N_ * 512);
  float* as1  = (float*)alloc(sizeof(float) * N_ * 4);
  float* ad1  = (float*)alloc(sizeof(float) * N_ * 4);
  float* as2  = (float*)alloc(sizeof(float) * N_);
  float* ad2  = (float*)alloc(sizeof(float) * N_);
  int* rowstart = (int*)alloc(sizeof(int) * (N_ + 1));
  int* cursor   = (int*)alloc(sizeof(int) * N_);
  int* csr      = (int*)alloc(sizeof(int) * TOT_EDGES);
  float* h2 = h1;  // alias: h1 dead after layer-1 aggregation

  const int waves_grid = (N_ * 64 + 255) / 256;  // 1 wave per node, 256-thread blocks

  // CSR build (independent of GEMM; same stream ordering is fine)
  zero_int<<<(N_ + 255) / 256, 256, 0, stream>>>(cursor, N_);
  count_kernel<<<(TOT_EDGES + 255) / 256, 256, 0, stream>>>(ei, cursor);
  scan_kernel<<<1, 256, 0, stream>>>(cursor, rowstart, cursor, N_);
  fill_kernel<<<(TOT_EDGES + 255) / 256, 256, 0, stream>>>(ei, cursor, csr);

  // layer 1: h1 = x @ W1 ; attention ; aggregate -> out1 (ELU inside)
  gemm_f32<64, 64, 64><<<dim3((N_ + 63) / 64, 512 / 64), 256, 0, stream>>>(
      x, W1, h1, N_, 512, 128);
  att_kernel<4, 128><<<waves_grid, 256, 0, stream>>>(h1, att_src1, att_dst1, as1, ad1, N_);
  aggregate_kernel<4, 128, true><<<waves_grid, 256, 0, stream>>>(
      h1, as1, ad1, rowstart, csr, bias1, out1, N_);

  // layer 2: h2 = out1 @ W2 ; attention ; aggregate -> out (ELU inside)
  gemm_f32<64, 64, 64><<<dim3((N_ + 63) / 64, 128 / 64), 256, 0, stream>>>(
      out1, W2, h2, N_, 128, 512);
  att_kernel<1, 128><<<waves_grid, 256, 0, stream>>>(h2, att_src2, att_dst2, as2, ad2, N_);
  aggregate_kernel<1, 128, true><<<waves_grid, 256, 0, stream>>>(
      h2, as2, ad2, rowstart, csr, bias2, out, N_);

  normalize_kernel<<<waves_grid, 256, 0, stream>>>(out, N_);
}

// Round 2
// 328.376 us; speedup vs baseline: 2.0007x; 2.0007x over previous
//
#include <hip/hip_runtime.h>
#include <cstddef>

#define N_NODES 50000
#define N_EDGES 400000
#define TOT_EDGES (N_EDGES + N_NODES)
#define M_PAD 50048    // 391 * 128  (GEMM row padding)
#define SCAN_PAD 50176 // 49 * 1024  (scan padding)

typedef _Float16 f16;
typedef __attribute__((ext_vector_type(8))) _Float16 f16x8;
typedef __attribute__((ext_vector_type(4))) _Float16 f16x4;
typedef __attribute__((ext_vector_type(2))) _Float16 f16x2;
typedef __attribute__((ext_vector_type(4))) float f32x4;

// ---------------------------------------------------------------------------
// CSR build (parallel scan version)
// ---------------------------------------------------------------------------
__global__ void zero_int(int* __restrict__ p, int n) {
  int i = blockIdx.x * blockDim.x + threadIdx.x;
  if (i < n) p[i] = 0;
}

__global__ void count_kernel(const int* __restrict__ ei, int* __restrict__ cnt) {
  int e = blockIdx.x * blockDim.x + threadIdx.x;
  if (e >= TOT_EDGES) return;
  int dst = (e < N_EDGES) ? ei[N_EDGES + e] : (e - N_EDGES);
  atomicAdd(&cnt[dst], 1);
}

// per-block scan: 256 threads x 4 items = 1024/block; cnt padded+zeroed to SCAN_PAD
__global__ __launch_bounds__(256) void block_scan(const int* __restrict__ cnt,
                                                  int* __restrict__ pre,
                                                  int* __restrict__ bsum) {
  __shared__ int wsum[4];
  const int t = threadIdx.x, lane = t & 63, w = t >> 6;
  const int base = blockIdx.x * 1024 + t * 4;
  int4 v = *(const int4*)&cnt[base];
  const int s = v.x + v.y + v.z + v.w;
  int x = s;
#pragma unroll
  for (int off = 1; off < 64; off <<= 1) {
    int y = __shfl_up(x, off);
    if (lane >= off) x += y;
  }
  if (lane == 63) wsum[w] = x;
  __syncthreads();
  int woff = 0;
  for (int j = 0; j < w; ++j) woff += wsum[j];
  const int ex = x - s + woff;  // exclusive prefix within block
  pre[base + 0] = ex;
  pre[base + 1] = ex + v.x;
  pre[base + 2] = ex + v.x + v.y;
  pre[base + 3] = ex + v.x + v.y + v.z;
  if (t == 255) bsum[blockIdx.x] = ex + s;  // block total
}

__global__ void bsum_scan(int* __restrict__ bsum, int nb) {  // 1 wave, in-place excl scan
  const int lane = threadIdx.x;
  int v = (lane < nb) ? bsum[lane] : 0;
  int x = v;
#pragma unroll
  for (int off = 1; off < 64; off <<= 1) {
    int y = __shfl_up(x, off);
    if (lane >= off) x += y;
  }
  if (lane < nb) bsum[lane] = x - v;
}

__global__ __launch_bounds__(256) void add_off(int* __restrict__ pre,
                                               const int* __restrict__ boff,
                                               int* __restrict__ cursor) {
  const int base = blockIdx.x * 1024 + threadIdx.x * 4;
  const int off = boff[blockIdx.x];
  int4 v = *(const int4*)&pre[base];
  v.x += off; v.y += off; v.z += off; v.w += off;
  *(int4*)&pre[base] = v;
  *(int4*)&cursor[base] = v;
}

__global__ void fill_kernel(const int* __restrict__ ei, int* __restrict__ cursor,
                            int* __restrict__ csr_src) {
  int e = blockIdx.x * blockDim.x + threadIdx.x;
  if (e >= TOT_EDGES) return;
  int s, d;
  if (e < N_EDGES) { s = ei[e]; d = ei[N_EDGES + e]; }
  else             { s = d = e - N_EDGES; }
  int pos = atomicAdd(&cursor[d], 1);
  csr_src[pos] = s;
}

// ---------------------------------------------------------------------------
// conversions
// ---------------------------------------------------------------------------
__global__ __launch_bounds__(256) void cvt_x(const float* __restrict__ x,
                                             f16* __restrict__ xb) {
  const size_t i = ((size_t)blockIdx.x * 256 + threadIdx.x) * 8;  // covers M_PAD*128
  f16x8 o;
  if (i < (size_t)N_NODES * 128) {
    float4 v0 = *(const float4*)&x[i];
    float4 v1 = *(const float4*)&x[i + 4];
    o[0] = (f16)v0.x; o[1] = (f16)v0.y; o[2] = (f16)v0.z; o[3] = (f16)v0.w;
    o[4] = (f16)v1.x; o[5] = (f16)v1.y; o[6] = (f16)v1.z; o[7] = (f16)v1.w;
  } else {
#pragma unroll
    for (int j = 0; j < 8; ++j) o[j] = (f16)0.f;
  }
  *(f16x8*)&xb[i] = o;
}

// W [R][C] f32 -> Wt [C][R] f16
__global__ __launch_bounds__(256) void cvt_w_t(const float* __restrict__ W,
                                               f16* __restrict__ Wt, int R, int C) {
  int idx = blockIdx.x * 256 + threadIdx.x;
  if (idx >= R * C) return;
  int cc = idx / R, rr = idx - cc * R;
  Wt[idx] = (f16)W[(size_t)rr * C + cc];
}

// V1s[k][h] = sum_d W1[k][h*128+d] * att_src1[h][d]   (128x4), same for dst
__global__ __launch_bounds__(256) void make_v1(const float* __restrict__ W1,
                                               const float* __restrict__ att_s,
                                               const float* __restrict__ att_d,
                                               float* __restrict__ V1s,
                                               float* __restrict__ V1d) {
  const int wid = (blockIdx.x * 256 + threadIdx.x) >> 6;  // 0..511
  const int lane = threadIdx.x & 63;
  const int k = wid >> 2, h = wid & 3;
  const float* wrow = W1 + (size_t)k * 512 + h * 128;
  float2 wv = *(const float2*)&wrow[lane * 2];
  float2 sv = *(const float2*)&att_s[h * 128 + lane * 2];
  float2 dv = *(const float2*)&att_d[h * 128 + lane * 2];
  float ps = wv.x * sv.x + wv.y * sv.y;
  float pd = wv.x * dv.x + wv.y * dv.y;
#pragma unroll
  for (int off = 32; off; off >>= 1) {
    ps += __shfl_xor(ps, off);
    pd += __shfl_xor(pd, off);
  }
  if (lane == 0) { V1s[k * 4 + h] = ps; V1d[k * 4 + h] = pd; }
}

// V2s[k] = sum_d W2[k][d] * att_src2[d]   (512), same for dst
__global__ __launch_bounds__(256) void make_v2(const float* __restrict__ W2,
                                               const float* __restrict__ att_s,
                                               const float* __restrict__ att_d,
                                               float* __restrict__ V2s,
                                               float* __restrict__ V2d) {
  const int wid = (blockIdx.x * 256 + threadIdx.x) >> 6;  // k = 0..511
  const int lane = threadIdx.x & 63;
  const float* wrow = W2 + (size_t)wid * 128;
  float2 wv = *(const float2*)&wrow[lane * 2];
  float2 sv = *(const float2*)&att_s[lane * 2];
  float2 dv = *(const float2*)&att_d[lane * 2];
  float ps = wv.x * sv.x + wv.y * sv.y;
  float pd = wv.x * dv.x + wv.y * dv.y;
#pragma unroll
  for (int off = 32; off; off >>= 1) {
    ps += __shfl_xor(ps, off);
    pd += __shfl_xor(pd, off);
  }
  if (lane == 0) { V2s[wid] = ps; V2d[wid] = pd; }
}

// a1[n][h] = x[n] . V1[:,h]  (fully f32; one wave per node)
__global__ __launch_bounds__(256) void a1_kernel(const float* __restrict__ x,
                                                 const float* __restrict__ V1s,
                                                 const float* __restrict__ V1d,
                                                 float* __restrict__ as1,
                                                 float* __restrict__ ad1, int n) {
  const int wid = (blockIdx.x * blockDim.x + threadIdx.x) >> 6;
  const int lane = threadIdx.x & 63;
  if (wid >= n) return;
  const int k = lane * 2;
  float2 xv = *(const float2*)&x[(size_t)wid * 128 + k];
  float4 vs0 = *(const float4*)&V1s[k * 4];
  float4 vs1 = *(const float4*)&V1s[(k + 1) * 4];
  float4 vd0 = *(const float4*)&V1d[k * 4];
  float4 vd1 = *(const float4*)&V1d[(k + 1) * 4];
  float s[4], d[4];
  s[0] = xv.x * vs0.x + xv.y * vs1.x;
  s[1] = xv.x * vs0.y + xv.y * vs1.y;
  s[2] = xv.x * vs0.z + xv.y * vs1.z;
  s[3] = xv.x * vs0.w + xv.y * vs1.w;
  d[0] = xv.x * vd0.x + xv.y * vd1.x;
  d[1] = xv.x * vd0.y + xv.y * vd1.y;
  d[2] = xv.x * vd0.z + xv.y * vd1.z;
  d[3] = xv.x * vd0.w + xv.y * vd1.w;
#pragma unroll
  for (int h = 0; h < 4; ++h) {
#pragma unroll
    for (int off = 32; off; off >>= 1) {
      s[h] += __shfl_xor(s[h], off);
      d[h] += __shfl_xor(d[h], off);
    }
  }
  if (lane == 0) {
    *(float4*)&as1[(size_t)wid * 4] = make_float4(s[0], s[1], s[2], s[3]);
    *(float4*)&ad1[(size_t)wid * 4] = make_float4(d[0], d[1], d[2], d[3]);
  }
}

// a2[n] = out1[n] . V2   (out1 is f16)
__global__ __launch_bounds__(256) void a2_kernel(const f16* __restrict__ h,
                                                 const float* __restrict__ V2s,
                                                 const float* __restrict__ V2d,
                                                 float* __restrict__ as2,
                                                 float* __restrict__ ad2, int n) {
  const int wid = (blockIdx.x * blockDim.x + threadIdx.x) >> 6;
  const int lane = threadIdx.x & 63;
  if (wid >= n) return;
  const int k = lane * 8;
  f16x8 hv = *(const f16x8*)&h[(size_t)wid * 512 + k];
  float4 vsa = *(const float4*)&V2s[k];
  float4 vsb = *(const float4*)&V2s[k + 4];
  float4 vda = *(const float4*)&V2d[k];
  float4 vdb = *(const float4*)&V2d[k + 4];
  float s = (float)hv[0] * vsa.x + (float)hv[1] * vsa.y + (float)hv[2] * vsa.z +
            (float)hv[3] * vsa.w + (float)hv[4] * vsb.x + (float)hv[5] * vsb.y +
            (float)hv[6] * vsb.z + (float)hv[7] * vsb.w;
  float d = (float)hv[0] * vda.x + (float)hv[1] * vda.y + (float)hv[2] * vda.z +
            (float)hv[3] * vda.w + (float)hv[4] * vdb.x + (float)hv[5] * vdb.y +
            (float)hv[6] * vdb.z + (float)hv[7] * vdb.w;
#pragma unroll
  for (int off = 32; off; off >>= 1) {
    s += __shfl_xor(s, off);
    d += __shfl_xor(d, off);
  }
  if (lane == 0) { as2[wid] = s; ad2[wid] = d; }
}

// ---------------------------------------------------------------------------
// MFMA GEMM: C[M_PAD][N] f16 = A[M_PAD][K] f16 @ Bt[N][K]^T f16  (f32 accum)
// block = 256 (4 waves), tile 128x128, BK=32. Wave (wr,wc) owns 64x64.
// LDS rows hold K=32 in the per-lane-group permuted order so fragment reads
// are single ds_read_b128; identical permutation for A and B (cancels in MFMA).
// ---------------------------------------------------------------------------
template <int K>
__global__ __launch_bounds__(256) void gemm_bt_f16(const f16* __restrict__ A,
                                                   const f16* __restrict__ Bt,
                                                   f16* __restrict__ C, int N) {
  constexpr int LDT = 40;  // padded row stride (elems); 80B = 16B-aligned
  __shared__ __align__(16) f16 As[128 * LDT];
  __shared__ __align__(16) f16 Bs[128 * LDT];
  const int tid = threadIdx.x;
  const int lane = tid & 63;
  const int g = lane >> 4, r16 = lane & 15;
  const int w = tid >> 6, wr = w >> 1, wc = w & 1;
  const long bm = (long)blockIdx.x * 128, bn = (long)blockIdx.y * 128;

  // staging: chunk c in [0,512): row=c>>2, h=c&3 (16B of global row). This
  // thread stages chunks {tid, tid+256} for both A and B.
  const int row0 = tid >> 2, h0 = tid & 3;
  const int p1 = (h0 & 1) * 16 + (h0 >> 1) * 4;  // permuted dest (elems)
  const long ga0 = (bm + row0) * (long)K + h0 * 8;
  const long ga1 = (bm + row0 + 64) * (long)K + h0 * 8;
  const long gb0 = (bn + row0) * (long)K + h0 * 8;
  const long gb1 = (bn + row0 + 64) * (long)K + h0 * 8;
  const int la0 = row0 * LDT + p1, la1 = (row0 + 64) * LDT + p1;

  f32x4 acc[4][4] = {};

  for (int k0 = 0; k0 < K; k0 += 32) {
    __syncthreads();
    f16x8 va0 = *(const f16x8*)&A[ga0 + k0];
    f16x8 va1 = *(const f16x8*)&A[ga1 + k0];
    f16x8 vb0 = *(const f16x8*)&Bt[gb0 + k0];
    f16x8 vb1 = *(const f16x8*)&Bt[gb1 + k0];
    *(f16x4*)&As[la0]     = __builtin_shufflevector(va0, va0, 0, 1, 2, 3);
    *(f16x4*)&As[la0 + 8] = __builtin_shufflevector(va0, va0, 4, 5, 6, 7);
    *(f16x4*)&As[la1]     = __builtin_shufflevector(va1, va1, 0, 1, 2, 3);
    *(f16x4*)&As[la1 + 8] = __builtin_shufflevector(va1, va1, 4, 5, 6, 7);
    *(f16x4*)&Bs[la0]     = __builtin_shufflevector(vb0, vb0, 0, 1, 2, 3);
    *(f16x4*)&Bs[la0 + 8] = __builtin_shufflevector(vb0, vb0, 4, 5, 6, 7);
    *(f16x4*)&Bs[la1]     = __builtin_shufflevector(vb1, vb1, 0, 1, 2, 3);
    *(f16x4*)&Bs[la1 + 8] = __builtin_shufflevector(vb1, vb1, 4, 5, 6, 7);
    __syncthreads();
    f16x8 af[4], bfv[4];
#pragma unroll
    for (int m = 0; m < 4; ++m)
      af[m] = *(const f16x8*)&As[(wr * 64 + m * 16 + r16) * LDT + g * 8];
#pragma unroll
    for (int n = 0; n < 4; ++n)
      bfv[n] = *(const f16x8*)&Bs[(wc * 64 + n * 16 + r16) * LDT + g * 8];
#pragma unroll
    for (int m = 0; m < 4; ++m)
#pragma unroll
      for (int n = 0; n < 4; ++n)
        acc[m][n] = __builtin_amdgcn_mfma_f32_16x16x32_f16(af[m], bfv[n], acc[m][n], 0, 0, 0);
  }

  // C/D layout (HW-verified): col = lane&15, row = 4*(lane>>4) + reg
#pragma unroll
  for (int m = 0; m < 4; ++m) {
#pragma unroll
    for (int n = 0; n < 4; ++n) {
      const long row = bm + wr * 64 + m * 16 + g * 4;
      const long col = bn + wc * 64 + n * 16 + r16;
#pragma unroll
      for (int r = 0; r < 4; ++r)
        C[(row + r) * N + col] = (f16)acc[m][n][r];
    }
  }
}

// ---------------------------------------------------------------------------
// layer-1 aggregation (H=4, D=128): f16 gather, f32 softmax, f16 out (ELU)
// ---------------------------------------------------------------------------
__global__ __launch_bounds__(256) void aggregate1(
    const f16* __restrict__ hsrc, const float* __restrict__ a_src,
    const float* __restrict__ a_dst, const int* __restrict__ rowstart,
    const int* __restrict__ csr, const float* __restrict__ bias,
    f16* __restrict__ outb, int n) {
  const int wid = (blockIdx.x * blockDim.x + threadIdx.x) >> 6;
  const int lane = threadIdx.x & 63;
  if (wid >= n) return;
  const int rs = rowstart[wid], re = rowstart[wid + 1];
  float4 adv = *(const float4*)&a_dst[(size_t)wid * 4];
  float ad4[4] = {adv.x, adv.y, adv.z, adv.w};

  float mx[4] = {-1e30f, -1e30f, -1e30f, -1e30f};
  for (int k = rs + lane; k < re; k += 64) {
    const int s = csr[k];
    float4 av = *(const float4*)&a_src[(size_t)s * 4];
    float ev[4] = {av.x, av.y, av.z, av.w};
#pragma unroll
    for (int h = 0; h < 4; ++h) {
      float e = ev[h] + ad4[h];
      e = e > 0.f ? e : 0.2f * e;
      mx[h] = fmaxf(mx[h], e);
    }
  }
#pragma unroll
  for (int h = 0; h < 4; ++h)
    for (int off = 32; off; off >>= 1) mx[h] = fmaxf(mx[h], __shfl_xor(mx[h], off));

  float sm[4] = {};
  for (int k = rs + lane; k < re; k += 64) {
    const int s = csr[k];
    float4 av = *(const float4*)&a_src[(size_t)s * 4];
    float ev[4] = {av.x, av.y, av.z, av.w};
#pragma unroll
    for (int h = 0; h < 4; ++h) {
      float e = ev[h] + ad4[h];
      e = e > 0.f ? e : 0.2f * e;
      sm[h] += __expf(e - mx[h]);
    }
  }
#pragma unroll
  for (int h = 0; h < 4; ++h) {
    for (int off = 32; off; off >>= 1) sm[h] += __shfl_xor(sm[h], off);
    sm[h] = 1.f / (sm[h] + 1e-16f);
  }

  const int col0 = lane * 8;
  const int hd = lane >> 4;
  const float mh = mx[hd], sh = sm[hd], adh = ad4[hd];
  float acc[8] = {};
  for (int k = rs; k < re; ++k) {
    const int s = csr[k];
    float e = a_src[(size_t)s * 4 + hd] + adh;
    e = e > 0.f ? e : 0.2f * e;
    const float alpha = __expf(e - mh) * sh;
    f16x8 hv = *(const f16x8*)&hsrc[(size_t)s * 512 + col0];
#pragma unroll
    for (int j = 0; j < 8; ++j) acc[j] += alpha * (float)hv[j];
  }
  f16x8 o;
#pragma unroll
  for (int j = 0; j < 8; ++j) {
    float v = acc[j] + bias[col0 + j];
    v = v > 0.f ? v : (__expf(v) - 1.f);
    o[j] = (f16)v;
  }
  *(f16x8*)&outb[(size_t)wid * 512 + col0] = o;
}

// ---------------------------------------------------------------------------
// layer-2 aggregation (H=1, D=128): f16 gather, f32 out (+bias, ELU)
// ---------------------------------------------------------------------------
__global__ __launch_bounds__(256) void aggregate2(
    const f16* __restrict__ hsrc, const float* __restrict__ a_src,
    const float* __restrict__ a_dst, const int* __restrict__ rowstart,
    const int* __restrict__ csr, const float* __restrict__ bias,
    float* __restrict__ out, int n) {
  const int wid = (blockIdx.x * blockDim.x + threadIdx.x) >> 6;
  const int lane = threadIdx.x & 63;
  if (wid >= n) return;
  const int rs = rowstart[wid], re = rowstart[wid + 1];
  const float ad = a_dst[wid];
  float mx = -1e30f;
  for (int k = rs + lane; k < re; k += 64) {
    float e = a_src[csr[k]] + ad;
    e = e > 0.f ? e : 0.2f * e;
    mx = fmaxf(mx, e);
  }
  for (int off = 32; off; off >>= 1) mx = fmaxf(mx, __shfl_xor(mx, off));
  float sm = 0.f;
  for (int k = rs + lane; k < re; k += 64) {
    float e = a_src[csr[k]] + ad;
    e = e > 0.f ? e : 0.2f * e;
    sm += __expf(e - mx);
  }
  for (int off = 32; off; off >>= 1) sm += __shfl_xor(sm, off);
  sm = 1.f / (sm + 1e-16f);
  const int col0 = lane * 2;
  float a0 = 0.f, a1 = 0.f;
  for (int k = rs; k < re; ++k) {
    const int s = csr[k];
    float e = a_src[s] + ad;
    e = e > 0.f ? e : 0.2f * e;
    const float alpha = __expf(e - mx) * sm;
    f16x2 hv = *(const f16x2*)&hsrc[(size_t)s * 128 + col0];
    a0 += alpha * (float)hv[0];
    a1 += alpha * (float)hv[1];
  }
  float v0 = a0 + bias[col0], v1 = a1 + bias[col0 + 1];
  v0 = v0 > 0.f ? v0 : (__expf(v0) - 1.f);
  v1 = v1 > 0.f ? v1 : (__expf(v1) - 1.f);
  float2 o; o.x = v0; o.y = v1;
  *(float2*)&out[(size_t)wid * 128 + col0] = o;
}

// ---------------------------------------------------------------------------
__global__ __launch_bounds__(256) void normalize_kernel(float* __restrict__ z, int n) {
  const int wid = (blockIdx.x * blockDim.x + threadIdx.x) >> 6;
  const int lane = threadIdx.x & 63;
  if (wid >= n) return;
  float* p = z + (size_t)wid * 128 + lane * 2;
  float2 v = *(float2*)p;
  float s = v.x * v.x + v.y * v.y;
#pragma unroll
  for (int off = 32; off; off >>= 1) s += __shfl_xor(s, off);
  float inv = 1.f / fmaxf(sqrtf(s), 1e-12f);
  v.x *= inv;
  v.y *= inv;
  *(float2*)p = v;
}

// ---------------------------------------------------------------------------
extern "C" void kernel_launch(void* const* d_in, const int* in_sizes, int n_in,
                              void* d_out, int out_size, void* d_ws, size_t ws_size,
                              hipStream_t stream) {
  const float* x        = (const float*)d_in[0];
  const int*   ei       = (const int*)d_in[1];
  const float* W1       = (const float*)d_in[2];
  const float* att_src1 = (const float*)d_in[3];
  const float* att_dst1 = (const float*)d_in[4];
  const float* bias1    = (const float*)d_in[5];
  const float* W2       = (const float*)d_in[6];
  const float* att_src2 = (const float*)d_in[7];
  const float* att_dst2 = (const float*)d_in[8];
  const float* bias2    = (const float*)d_in[9];
  float* out = (float*)d_out;

  char* ws = (char*)d_ws;
  size_t off = 0;
  auto alloc = [&](size_t bytes) {
    char* p = ws + off;
    off = (off + bytes + 255) & ~(size_t)255;
    return p;
  };
  f16* xb    = (f16*)alloc(sizeof(f16) * (size_t)M_PAD * 128);
  f16* w1t   = (f16*)alloc(sizeof(f16) * 512 * 128);
  f16* w2t   = (f16*)alloc(sizeof(f16) * 128 * 512);
  f16* h1b   = (f16*)alloc(sizeof(f16) * (size_t)M_PAD * 512);
  f16* out1b = (f16*)alloc(sizeof(f16) * (size_t)M_PAD * 512);
  float* V1s = (float*)alloc(sizeof(float) * 512);
  float* V1d = (float*)alloc(sizeof(float) * 512);
  float* V2s = (float*)alloc(sizeof(float) * 512);
  float* V2d = (float*)alloc(sizeof(float) * 512);
  float* as1 = (float*)alloc(sizeof(float) * N_NODES * 4);
  float* ad1 = (float*)alloc(sizeof(float) * N_NODES * 4);
  float* as2 = (float*)alloc(sizeof(float) * N_NODES);
  float* ad2 = (float*)alloc(sizeof(float) * N_NODES);
  int* rowstart = (int*)alloc(sizeof(int) * (SCAN_PAD + 4));
  int* cursor   = (int*)alloc(sizeof(int) * SCAN_PAD);
  int* bsum     = (int*)alloc(sizeof(int) * 64);
  int* csr      = (int*)alloc(sizeof(int) * TOT_EDGES);
  f16* h2b = h1b;  // alias: h1b dead after aggregate1

  const int wgrid = (N_NODES * 64) / 256;  // 12500 blocks, 1 wave/node

  // CSR build
  zero_int<<<(SCAN_PAD + 255) / 256, 256, 0, stream>>>(cursor, SCAN_PAD);
  count_kernel<<<(TOT_EDGES + 255) / 256, 256, 0, stream>>>(ei, cursor);
  block_scan<<<49, 256, 0, stream>>>(cursor, rowstart, bsum);
  bsum_scan<<<1, 64, 0, stream>>>(bsum, 49);
  add_off<<<49, 256, 0, stream>>>(rowstart, bsum, cursor);
  fill_kernel<<<(TOT_EDGES + 255) / 256, 256, 0, stream>>>(ei, cursor, csr);

  // conversions + attention projection vectors
  cvt_x<<<(M_PAD * 128 / 8 + 255) / 256, 256, 0, stream>>>(x, xb);
  cvt_w_t<<<(512 * 128 + 255) / 256, 256, 0, stream>>>(W1, w1t, 128, 512);
  cvt_w_t<<<(512 * 128 + 255) / 256, 256, 0, stream>>>(W2, w2t, 512, 128);
  make_v1<<<128, 256, 0, stream>>>(W1, att_src1, att_dst1, V1s, V1d);
  make_v2<<<128, 256, 0, stream>>>(W2, att_src2, att_dst2, V2s, V2d);

  // layer 1
  gemm_bt_f16<128><<<dim3(M_PAD / 128, 4), 256, 0, stream>>>(xb, w1t, h1b, 512);
  a1_kernel<<<wgrid, 256, 0, stream>>>(x, V1s, V1d, as1, ad1, N_NODES);
  aggregate1<<<wgrid, 256, 0, stream>>>(h1b, as1, ad1, rowstart, csr, bias1, out1b, N_NODES);

  // layer 2
  gemm_bt_f16<512><<<dim3(M_PAD / 128, 1), 256, 0, stream>>>(out1b, w2t, h2b, 128);
  a2_kernel<<<wgrid, 256, 0, stream>>>(out1b, V2s, V2d, as2, ad2, N_NODES);
  aggregate2<<<wgrid, 256, 0, stream>>>(h2b, as2, ad2, rowstart, csr, bias2, out, N_NODES);

  normalize_kernel<<<wgrid, 256, 0, stream>>>(out, N_NODES);
}

// Round 3
// 247.359 us; speedup vs baseline: 2.6560x; 1.3275x over previous
//
#include <hip/hip_runtime.h>
#include <cstddef>

#define N_NODES 50000
#define N_EDGES 400000
#define TOT_EDGES (N_EDGES + N_NODES)
#define M_PAD 50048    // 391 * 128  (GEMM row padding)
#define SCAN_PAD 50176 // 49 * 1024  (scan padding)

typedef _Float16 f16;
typedef __attribute__((ext_vector_type(8))) _Float16 f16x8;
typedef __attribute__((ext_vector_type(4))) _Float16 f16x4;
typedef __attribute__((ext_vector_type(2))) _Float16 f16x2;
typedef __attribute__((ext_vector_type(4))) float f32x4;

__device__ __forceinline__ int rfl(int v) { return __builtin_amdgcn_readfirstlane(v); }
__device__ __forceinline__ float rdlane_f(float v, int l) {
  return __int_as_float(__builtin_amdgcn_readlane(__float_as_int(v), l));
}

// ---------------------------------------------------------------------------
// CSR build (parallel scan version)
// ---------------------------------------------------------------------------
__global__ void zero_int(int* __restrict__ p, int n) {
  int i = blockIdx.x * blockDim.x + threadIdx.x;
  if (i < n) p[i] = 0;
}

__global__ void count_kernel(const int* __restrict__ ei, int* __restrict__ cnt) {
  int e = blockIdx.x * blockDim.x + threadIdx.x;
  if (e >= TOT_EDGES) return;
  int dst = (e < N_EDGES) ? ei[N_EDGES + e] : (e - N_EDGES);
  atomicAdd(&cnt[dst], 1);
}

__global__ __launch_bounds__(256) void block_scan(const int* __restrict__ cnt,
                                                  int* __restrict__ pre,
                                                  int* __restrict__ bsum) {
  __shared__ int wsum[4];
  const int t = threadIdx.x, lane = t & 63, w = t >> 6;
  const int base = blockIdx.x * 1024 + t * 4;
  int4 v = *(const int4*)&cnt[base];
  const int s = v.x + v.y + v.z + v.w;
  int x = s;
#pragma unroll
  for (int off = 1; off < 64; off <<= 1) {
    int y = __shfl_up(x, off);
    if (lane >= off) x += y;
  }
  if (lane == 63) wsum[w] = x;
  __syncthreads();
  int woff = 0;
  for (int j = 0; j < w; ++j) woff += wsum[j];
  const int ex = x - s + woff;  // exclusive prefix within block
  pre[base + 0] = ex;
  pre[base + 1] = ex + v.x;
  pre[base + 2] = ex + v.x + v.y;
  pre[base + 3] = ex + v.x + v.y + v.z;
  if (t == 255) bsum[blockIdx.x] = ex + s;
}

__global__ void bsum_scan(int* __restrict__ bsum, int nb) {
  const int lane = threadIdx.x;
  int v = (lane < nb) ? bsum[lane] : 0;
  int x = v;
#pragma unroll
  for (int off = 1; off < 64; off <<= 1) {
    int y = __shfl_up(x, off);
    if (lane >= off) x += y;
  }
  if (lane < nb) bsum[lane] = x - v;
}

__global__ __launch_bounds__(256) void add_off(int* __restrict__ pre,
                                               const int* __restrict__ boff,
                                               int* __restrict__ cursor) {
  const int base = blockIdx.x * 1024 + threadIdx.x * 4;
  const int off = boff[blockIdx.x];
  int4 v = *(const int4*)&pre[base];
  v.x += off; v.y += off; v.z += off; v.w += off;
  *(int4*)&pre[base] = v;
  *(int4*)&cursor[base] = v;
}

__global__ void fill_kernel(const int* __restrict__ ei, int* __restrict__ cursor,
                            int* __restrict__ csr_src) {
  int e = blockIdx.x * blockDim.x + threadIdx.x;
  if (e >= TOT_EDGES) return;
  int s, d;
  if (e < N_EDGES) { s = ei[e]; d = ei[N_EDGES + e]; }
  else             { s = d = e - N_EDGES; }
  int pos = atomicAdd(&cursor[d], 1);
  csr_src[pos] = s;
}

// ---------------------------------------------------------------------------
// prep_x: x(f32) -> xb(f16, M_PAD rows, zero-padded)  +  a1 = x . V1 (f32)
// one wave per row
// ---------------------------------------------------------------------------
__global__ __launch_bounds__(256) void prep_x(const float* __restrict__ x,
                                              f16* __restrict__ xb,
                                              const float* __restrict__ V1s,
                                              const float* __restrict__ V1d,
                                              float* __restrict__ as1,
                                              float* __restrict__ ad1) {
  const int wid = (blockIdx.x * 256 + threadIdx.x) >> 6;
  const int lane = threadIdx.x & 63;
  if (wid >= M_PAD) return;
  const int k = lane * 2;
  if (wid >= N_NODES) {
    f16x2 z; z[0] = (f16)0.f; z[1] = (f16)0.f;
    *(f16x2*)&xb[(size_t)wid * 128 + k] = z;
    return;
  }
  float2 xv = *(const float2*)&x[(size_t)wid * 128 + k];
  f16x2 o; o[0] = (f16)xv.x; o[1] = (f16)xv.y;
  *(f16x2*)&xb[(size_t)wid * 128 + k] = o;

  float4 vs0 = *(const float4*)&V1s[k * 4];
  float4 vs1 = *(const float4*)&V1s[(k + 1) * 4];
  float4 vd0 = *(const float4*)&V1d[k * 4];
  float4 vd1 = *(const float4*)&V1d[(k + 1) * 4];
  float s[4], d[4];
  s[0] = xv.x * vs0.x + xv.y * vs1.x;
  s[1] = xv.x * vs0.y + xv.y * vs1.y;
  s[2] = xv.x * vs0.z + xv.y * vs1.z;
  s[3] = xv.x * vs0.w + xv.y * vs1.w;
  d[0] = xv.x * vd0.x + xv.y * vd1.x;
  d[1] = xv.x * vd0.y + xv.y * vd1.y;
  d[2] = xv.x * vd0.z + xv.y * vd1.z;
  d[3] = xv.x * vd0.w + xv.y * vd1.w;
#pragma unroll
  for (int h = 0; h < 4; ++h) {
#pragma unroll
    for (int off = 32; off; off >>= 1) {
      s[h] += __shfl_xor(s[h], off);
      d[h] += __shfl_xor(d[h], off);
    }
  }
  if (lane == 0) {
    *(float4*)&as1[(size_t)wid * 4] = make_float4(s[0], s[1], s[2], s[3]);
    *(float4*)&ad1[(size_t)wid * 4] = make_float4(d[0], d[1], d[2], d[3]);
  }
}

// W [R][C] f32 -> Wt [C][R] f16
__global__ __launch_bounds__(256) void cvt_w_t(const float* __restrict__ W,
                                               f16* __restrict__ Wt, int R, int C) {
  int idx = blockIdx.x * 256 + threadIdx.x;
  if (idx >= R * C) return;
  int cc = idx / R, rr = idx - cc * R;
  Wt[idx] = (f16)W[(size_t)rr * C + cc];
}

__global__ __launch_bounds__(256) void make_v1(const float* __restrict__ W1,
                                               const float* __restrict__ att_s,
                                               const float* __restrict__ att_d,
                                               float* __restrict__ V1s,
                                               float* __restrict__ V1d) {
  const int wid = (blockIdx.x * 256 + threadIdx.x) >> 6;  // 0..511
  const int lane = threadIdx.x & 63;
  const int k = wid >> 2, h = wid & 3;
  const float* wrow = W1 + (size_t)k * 512 + h * 128;
  float2 wv = *(const float2*)&wrow[lane * 2];
  float2 sv = *(const float2*)&att_s[h * 128 + lane * 2];
  float2 dv = *(const float2*)&att_d[h * 128 + lane * 2];
  float ps = wv.x * sv.x + wv.y * sv.y;
  float pd = wv.x * dv.x + wv.y * dv.y;
#pragma unroll
  for (int off = 32; off; off >>= 1) {
    ps += __shfl_xor(ps, off);
    pd += __shfl_xor(pd, off);
  }
  if (lane == 0) { V1s[k * 4 + h] = ps; V1d[k * 4 + h] = pd; }
}

__global__ __launch_bounds__(256) void make_v2(const float* __restrict__ W2,
                                               const float* __restrict__ att_s,
                                               const float* __restrict__ att_d,
                                               float* __restrict__ V2s,
                                               float* __restrict__ V2d) {
  const int wid = (blockIdx.x * 256 + threadIdx.x) >> 6;  // k = 0..511
  const int lane = threadIdx.x & 63;
  const float* wrow = W2 + (size_t)wid * 128;
  float2 wv = *(const float2*)&wrow[lane * 2];
  float2 sv = *(const float2*)&att_s[lane * 2];
  float2 dv = *(const float2*)&att_d[lane * 2];
  float ps = wv.x * sv.x + wv.y * sv.y;
  float pd = wv.x * dv.x + wv.y * dv.y;
#pragma unroll
  for (int off = 32; off; off >>= 1) {
    ps += __shfl_xor(ps, off);
    pd += __shfl_xor(pd, off);
  }
  if (lane == 0) { V2s[wid] = ps; V2d[wid] = pd; }
}

// ---------------------------------------------------------------------------
// MFMA GEMM (unchanged from round 1)
// ---------------------------------------------------------------------------
template <int K>
__global__ __launch_bounds__(256) void gemm_bt_f16(const f16* __restrict__ A,
                                                   const f16* __restrict__ Bt,
                                                   f16* __restrict__ C, int N) {
  constexpr int LDT = 40;
  __shared__ __align__(16) f16 As[128 * LDT];
  __shared__ __align__(16) f16 Bs[128 * LDT];
  const int tid = threadIdx.x;
  const int lane = tid & 63;
  const int g = lane >> 4, r16 = lane & 15;
  const int w = tid >> 6, wr = w >> 1, wc = w & 1;
  const long bm = (long)blockIdx.x * 128, bn = (long)blockIdx.y * 128;

  const int row0 = tid >> 2, h0 = tid & 3;
  const int p1 = (h0 & 1) * 16 + (h0 >> 1) * 4;
  const long ga0 = (bm + row0) * (long)K + h0 * 8;
  const long ga1 = (bm + row0 + 64) * (long)K + h0 * 8;
  const long gb0 = (bn + row0) * (long)K + h0 * 8;
  const long gb1 = (bn + row0 + 64) * (long)K + h0 * 8;
  const int la0 = row0 * LDT + p1, la1 = (row0 + 64) * LDT + p1;

  f32x4 acc[4][4] = {};

  for (int k0 = 0; k0 < K; k0 += 32) {
    __syncthreads();
    f16x8 va0 = *(const f16x8*)&A[ga0 + k0];
    f16x8 va1 = *(const f16x8*)&A[ga1 + k0];
    f16x8 vb0 = *(const f16x8*)&Bt[gb0 + k0];
    f16x8 vb1 = *(const f16x8*)&Bt[gb1 + k0];
    *(f16x4*)&As[la0]     = __builtin_shufflevector(va0, va0, 0, 1, 2, 3);
    *(f16x4*)&As[la0 + 8] = __builtin_shufflevector(va0, va0, 4, 5, 6, 7);
    *(f16x4*)&As[la1]     = __builtin_shufflevector(va1, va1, 0, 1, 2, 3);
    *(f16x4*)&As[la1 + 8] = __builtin_shufflevector(va1, va1, 4, 5, 6, 7);
    *(f16x4*)&Bs[la0]     = __builtin_shufflevector(vb0, vb0, 0, 1, 2, 3);
    *(f16x4*)&Bs[la0 + 8] = __builtin_shufflevector(vb0, vb0, 4, 5, 6, 7);
    *(f16x4*)&Bs[la1]     = __builtin_shufflevector(vb1, vb1, 0, 1, 2, 3);
    *(f16x4*)&Bs[la1 + 8] = __builtin_shufflevector(vb1, vb1, 4, 5, 6, 7);
    __syncthreads();
    f16x8 af[4], bfv[4];
#pragma unroll
    for (int m = 0; m < 4; ++m)
      af[m] = *(const f16x8*)&As[(wr * 64 + m * 16 + r16) * LDT + g * 8];
#pragma unroll
    for (int n = 0; n < 4; ++n)
      bfv[n] = *(const f16x8*)&Bs[(wc * 64 + n * 16 + r16) * LDT + g * 8];
#pragma unroll
    for (int m = 0; m < 4; ++m)
#pragma unroll
      for (int n = 0; n < 4; ++n)
        acc[m][n] = __builtin_amdgcn_mfma_f32_16x16x32_f16(af[m], bfv[n], acc[m][n], 0, 0, 0);
  }

#pragma unroll
  for (int m = 0; m < 4; ++m) {
#pragma unroll
    for (int n = 0; n < 4; ++n) {
      const long row = bm + wr * 64 + m * 16 + g * 4;
      const long col = bn + wc * 64 + n * 16 + r16;
#pragma unroll
      for (int r = 0; r < 4; ++r)
        C[(row + r) * N + col] = (f16)acc[m][n][r];
    }
  }
}

// ---------------------------------------------------------------------------
// layer-1 aggregation (H=4, D=128): no-max softmax, scalarized edge loop,
// fused a2 = out1 . V2 epilogue.
// lane layout: sub = lane&15 (edge slot), hd = lane>>4 (head)
// ---------------------------------------------------------------------------
__global__ __launch_bounds__(256) void aggregate1(
    const f16* __restrict__ hsrc, const float* __restrict__ a_src,
    const float* __restrict__ a_dst, const int* __restrict__ rowstart,
    const int* __restrict__ csr, const float* __restrict__ bias,
    const float* __restrict__ V2s, const float* __restrict__ V2d,
    f16* __restrict__ outb, float* __restrict__ as2, float* __restrict__ ad2,
    int n) {
  const int wid0 = (blockIdx.x * blockDim.x + threadIdx.x) >> 6;
  if (wid0 >= n) return;
  const int wid = rfl(wid0);
  const int lane = threadIdx.x & 63;
  const int sub = lane & 15, hd = lane >> 4;
  const int rs = rfl(rowstart[wid]);
  const int re = rfl(rowstart[wid + 1]);
  const float adh = a_dst[(size_t)wid * 4 + hd];

  // denominator (no max-sub: logits bounded |e| < ~4; self-loop => denom > 0)
  float sum = 0.f;
  for (int c = rs; c < re; c += 16) {
    const int idx = c + sub;
    const bool ok = idx < re;
    const int s = ok ? csr[idx] : 0;
    float e = a_src[(size_t)s * 4 + hd] + adh;
    e = e > 0.f ? e : 0.2f * e;
    sum += ok ? __expf(e) : 0.f;
  }
  sum += __shfl_xor(sum, 1);
  sum += __shfl_xor(sum, 2);
  sum += __shfl_xor(sum, 4);
  sum += __shfl_xor(sum, 8);
  const float sh = 1.f / (sum + 1e-16f);

  const int col0 = lane * 8;
  const int bbase = (lane & 48) << 2;  // bpermute byte base of own head group
  float acc[8] = {};
  for (int c = rs; c < re; c += 16) {
    const int idx = c + sub;
    const bool ok = idx < re;
    const int s_l = ok ? csr[idx] : 0;
    float e = a_src[(size_t)s_l * 4 + hd] + adh;
    e = e > 0.f ? e : 0.2f * e;
    const float ex_l = ok ? __expf(e) : 0.f;
    const int cnt = min(16, re - c);
    for (int i = 0; i < cnt; ++i) {
      const int s = __builtin_amdgcn_readlane(s_l, i);  // uniform (head-0 lanes)
      const float exv = __int_as_float(
          __builtin_amdgcn_ds_bpermute(bbase + 4 * i, __float_as_int(ex_l)));
      const float alpha = exv * sh;
      const f16x8 hv = *(const f16x8*)&hsrc[(size_t)s * 512 + col0];
#pragma unroll
      for (int j = 0; j < 8; ++j) acc[j] += alpha * (float)hv[j];
    }
  }

  // epilogue: bias + ELU + f16 store; fused layer-2 attention dot
  float4 vsa = *(const float4*)&V2s[col0];
  float4 vsb = *(const float4*)&V2s[col0 + 4];
  float4 vda = *(const float4*)&V2d[col0];
  float4 vdb = *(const float4*)&V2d[col0 + 4];
  const float vs[8] = {vsa.x, vsa.y, vsa.z, vsa.w, vsb.x, vsb.y, vsb.z, vsb.w};
  const float vd[8] = {vda.x, vda.y, vda.z, vda.w, vdb.x, vdb.y, vdb.z, vdb.w};
  f16x8 o;
  float s2 = 0.f, d2 = 0.f;
#pragma unroll
  for (int j = 0; j < 8; ++j) {
    float v = acc[j] + bias[col0 + j];
    v = v > 0.f ? v : (__expf(v) - 1.f);
    o[j] = (f16)v;
    s2 += v * vs[j];
    d2 += v * vd[j];
  }
  *(f16x8*)&outb[(size_t)wid * 512 + col0] = o;
#pragma unroll
  for (int off = 32; off; off >>= 1) {
    s2 += __shfl_xor(s2, off);
    d2 += __shfl_xor(d2, off);
  }
  if (lane == 0) { as2[wid] = s2; ad2[wid] = d2; }
}

// ---------------------------------------------------------------------------
// layer-2 aggregation (H=1, D=128) + fused L2-normalize
// ---------------------------------------------------------------------------
__global__ __launch_bounds__(256) void aggregate2(
    const f16* __restrict__ hsrc, const float* __restrict__ a_src,
    const float* __restrict__ a_dst, const int* __restrict__ rowstart,
    const int* __restrict__ csr, const float* __restrict__ bias,
    float* __restrict__ out, int n) {
  const int wid0 = (blockIdx.x * blockDim.x + threadIdx.x) >> 6;
  if (wid0 >= n) return;
  const int wid = rfl(wid0);
  const int lane = threadIdx.x & 63;
  const int rs = rfl(rowstart[wid]);
  const int re = rfl(rowstart[wid + 1]);
  const float ad = a_dst[wid];

  float sum = 0.f;
  for (int c = rs; c < re; c += 64) {
    const int idx = c + lane;
    const bool ok = idx < re;
    const int s = ok ? csr[idx] : 0;
    float e = a_src[s] + ad;
    e = e > 0.f ? e : 0.2f * e;
    sum += ok ? __expf(e) : 0.f;
  }
#pragma unroll
  for (int off = 32; off; off >>= 1) sum += __shfl_xor(sum, off);
  const float sm = 1.f / (sum + 1e-16f);

  const int col0 = lane * 2;
  float a0 = 0.f, a1 = 0.f;
  for (int c = rs; c < re; c += 64) {
    const int idx = c + lane;
    const bool ok = idx < re;
    const int s_l = ok ? csr[idx] : 0;
    float e = a_src[s_l] + ad;
    e = e > 0.f ? e : 0.2f * e;
    const float ex_l = ok ? __expf(e) : 0.f;
    const int cnt = min(64, re - c);
    for (int i = 0; i < cnt; ++i) {
      const int s = __builtin_amdgcn_readlane(s_l, i);
      const float alpha = rdlane_f(ex_l, i) * sm;
      const f16x2 hv = *(const f16x2*)&hsrc[(size_t)s * 128 + col0];
      a0 += alpha * (float)hv[0];
      a1 += alpha * (float)hv[1];
    }
  }
  float v0 = a0 + bias[col0], v1 = a1 + bias[col0 + 1];
  v0 = v0 > 0.f ? v0 : (__expf(v0) - 1.f);
  v1 = v1 > 0.f ? v1 : (__expf(v1) - 1.f);
  float ss = v0 * v0 + v1 * v1;
#pragma unroll
  for (int off = 32; off; off >>= 1) ss += __shfl_xor(ss, off);
  const float inv = 1.f / fmaxf(sqrtf(ss), 1e-12f);
  float2 ov; ov.x = v0 * inv; ov.y = v1 * inv;
  *(float2*)&out[(size_t)wid * 128 + col0] = ov;
}

// ---------------------------------------------------------------------------
extern "C" void kernel_launch(void* const* d_in, const int* in_sizes, int n_in,
                              void* d_out, int out_size, void* d_ws, size_t ws_size,
                              hipStream_t stream) {
  const float* x        = (const float*)d_in[0];
  const int*   ei       = (const int*)d_in[1];
  const float* W1       = (const float*)d_in[2];
  const float* att_src1 = (const float*)d_in[3];
  const float* att_dst1 = (const float*)d_in[4];
  const float* bias1    = (const float*)d_in[5];
  const float* W2       = (const float*)d_in[6];
  const float* att_src2 = (const float*)d_in[7];
  const float* att_dst2 = (const float*)d_in[8];
  const float* bias2    = (const float*)d_in[9];
  float* out = (float*)d_out;

  char* ws = (char*)d_ws;
  size_t off = 0;
  auto alloc = [&](size_t bytes) {
    char* p = ws + off;
    off = (off + bytes + 255) & ~(size_t)255;
    return p;
  };
  f16* xb    = (f16*)alloc(sizeof(f16) * (size_t)M_PAD * 128);
  f16* w1t   = (f16*)alloc(sizeof(f16) * 512 * 128);
  f16* w2t   = (f16*)alloc(sizeof(f16) * 128 * 512);
  f16* h1b   = (f16*)alloc(sizeof(f16) * (size_t)M_PAD * 512);
  f16* out1b = (f16*)alloc(sizeof(f16) * (size_t)M_PAD * 512);
  float* V1s = (float*)alloc(sizeof(float) * 512);
  float* V1d = (float*)alloc(sizeof(float) * 512);
  float* V2s = (float*)alloc(sizeof(float) * 512);
  float* V2d = (float*)alloc(sizeof(float) * 512);
  float* as1 = (float*)alloc(sizeof(float) * N_NODES * 4);
  float* ad1 = (float*)alloc(sizeof(float) * N_NODES * 4);
  float* as2 = (float*)alloc(sizeof(float) * N_NODES);
  float* ad2 = (float*)alloc(sizeof(float) * N_NODES);
  int* rowstart = (int*)alloc(sizeof(int) * (SCAN_PAD + 4));
  int* cursor   = (int*)alloc(sizeof(int) * SCAN_PAD);
  int* bsum     = (int*)alloc(sizeof(int) * 64);
  int* csr      = (int*)alloc(sizeof(int) * TOT_EDGES);
  f16* h2b = h1b;  // alias: h1b dead after aggregate1

  const int wgrid = (N_NODES * 64) / 256;  // 12500 blocks, 1 wave/node

  // CSR build
  zero_int<<<(SCAN_PAD + 255) / 256, 256, 0, stream>>>(cursor, SCAN_PAD);
  count_kernel<<<(TOT_EDGES + 255) / 256, 256, 0, stream>>>(ei, cursor);
  block_scan<<<49, 256, 0, stream>>>(cursor, rowstart, bsum);
  bsum_scan<<<1, 64, 0, stream>>>(bsum, 49);
  add_off<<<49, 256, 0, stream>>>(rowstart, bsum, cursor);
  fill_kernel<<<(TOT_EDGES + 255) / 256, 256, 0, stream>>>(ei, cursor, csr);

  // weights + attention projection vectors
  make_v1<<<128, 256, 0, stream>>>(W1, att_src1, att_dst1, V1s, V1d);
  make_v2<<<128, 256, 0, stream>>>(W2, att_src2, att_dst2, V2s, V2d);
  cvt_w_t<<<(512 * 128 + 255) / 256, 256, 0, stream>>>(W1, w1t, 128, 512);
  cvt_w_t<<<(512 * 128 + 255) / 256, 256, 0, stream>>>(W2, w2t, 512, 128);
  prep_x<<<(M_PAD * 64) / 256, 256, 0, stream>>>(x, xb, V1s, V1d, as1, ad1);

  // layer 1
  gemm_bt_f16<128><<<dim3(M_PAD / 128, 4), 256, 0, stream>>>(xb, w1t, h1b, 512);
  aggregate1<<<wgrid, 256, 0, stream>>>(h1b, as1, ad1, rowstart, csr, bias1,
                                        V2s, V2d, out1b, as2, ad2, N_NODES);

  // layer 2
  gemm_bt_f16<512><<<dim3(M_PAD / 128, 1), 256, 0, stream>>>(out1b, w2t, h2b, 128);
  aggregate2<<<wgrid, 256, 0, stream>>>(h2b, as2, ad2, rowstart, csr, bias2, out, N_NODES);
}

// Round 4
// 241.057 us; speedup vs baseline: 2.7254x; 1.0261x over previous
//
#include <hip/hip_runtime.h>
#include <cstddef>

#define N_NODES 50000
#define N_EDGES 400000
#define TOT_EDGES (N_EDGES + N_NODES)
#define M_PAD 50048    // 391 * 128  (GEMM row padding)
#define SCAN_PAD 50176 // 49 * 1024  (scan padding)

typedef _Float16 f16;
typedef __attribute__((ext_vector_type(8))) _Float16 f16x8;
typedef __attribute__((ext_vector_type(4))) _Float16 f16x4;
typedef __attribute__((ext_vector_type(2))) _Float16 f16x2;
typedef __attribute__((ext_vector_type(4))) float f32x4;

__device__ __forceinline__ int rfl(int v) { return __builtin_amdgcn_readfirstlane(v); }

// ---------------------------------------------------------------------------
// CSR build (parallel scan version)
// ---------------------------------------------------------------------------
__global__ void zero_int(int* __restrict__ p, int n) {
  int i = blockIdx.x * blockDim.x + threadIdx.x;
  if (i < n) p[i] = 0;
}

__global__ void count_kernel(const int* __restrict__ ei, int* __restrict__ cnt) {
  int e = blockIdx.x * blockDim.x + threadIdx.x;
  if (e >= TOT_EDGES) return;
  int dst = (e < N_EDGES) ? ei[N_EDGES + e] : (e - N_EDGES);
  atomicAdd(&cnt[dst], 1);
}

__global__ __launch_bounds__(256) void block_scan(const int* __restrict__ cnt,
                                                  int* __restrict__ pre,
                                                  int* __restrict__ bsum) {
  __shared__ int wsum[4];
  const int t = threadIdx.x, lane = t & 63, w = t >> 6;
  const int base = blockIdx.x * 1024 + t * 4;
  int4 v = *(const int4*)&cnt[base];
  const int s = v.x + v.y + v.z + v.w;
  int x = s;
#pragma unroll
  for (int off = 1; off < 64; off <<= 1) {
    int y = __shfl_up(x, off);
    if (lane >= off) x += y;
  }
  if (lane == 63) wsum[w] = x;
  __syncthreads();
  int woff = 0;
  for (int j = 0; j < w; ++j) woff += wsum[j];
  const int ex = x - s + woff;  // exclusive prefix within block
  pre[base + 0] = ex;
  pre[base + 1] = ex + v.x;
  pre[base + 2] = ex + v.x + v.y;
  pre[base + 3] = ex + v.x + v.y + v.z;
  if (t == 255) bsum[blockIdx.x] = ex + s;
}

__global__ void bsum_scan(int* __restrict__ bsum, int nb) {
  const int lane = threadIdx.x;
  int v = (lane < nb) ? bsum[lane] : 0;
  int x = v;
#pragma unroll
  for (int off = 1; off < 64; off <<= 1) {
    int y = __shfl_up(x, off);
    if (lane >= off) x += y;
  }
  if (lane < nb) bsum[lane] = x - v;
}

__global__ __launch_bounds__(256) void add_off(int* __restrict__ pre,
                                               const int* __restrict__ boff,
                                               int* __restrict__ cursor) {
  const int base = blockIdx.x * 1024 + threadIdx.x * 4;
  const int off = boff[blockIdx.x];
  int4 v = *(const int4*)&pre[base];
  v.x += off; v.y += off; v.z += off; v.w += off;
  *(int4*)&pre[base] = v;
  *(int4*)&cursor[base] = v;
}

__global__ void fill_kernel(const int* __restrict__ ei, int* __restrict__ cursor,
                            int* __restrict__ csr_src) {
  int e = blockIdx.x * blockDim.x + threadIdx.x;
  if (e >= TOT_EDGES) return;
  int s, d;
  if (e < N_EDGES) { s = ei[e]; d = ei[N_EDGES + e]; }
  else             { s = d = e - N_EDGES; }
  int pos = atomicAdd(&cursor[d], 1);
  csr_src[pos] = s;
}

// ---------------------------------------------------------------------------
// prep_x: x(f32) -> xb(f16, M_PAD rows, zero-padded)  +  a1 = x . V1 (f32)
// ---------------------------------------------------------------------------
__global__ __launch_bounds__(256) void prep_x(const float* __restrict__ x,
                                              f16* __restrict__ xb,
                                              const float* __restrict__ V1s,
                                              const float* __restrict__ V1d,
                                              float* __restrict__ as1,
                                              float* __restrict__ ad1) {
  const int wid = (blockIdx.x * 256 + threadIdx.x) >> 6;
  const int lane = threadIdx.x & 63;
  if (wid >= M_PAD) return;
  const int k = lane * 2;
  if (wid >= N_NODES) {
    f16x2 z; z[0] = (f16)0.f; z[1] = (f16)0.f;
    *(f16x2*)&xb[(size_t)wid * 128 + k] = z;
    return;
  }
  float2 xv = *(const float2*)&x[(size_t)wid * 128 + k];
  f16x2 o; o[0] = (f16)xv.x; o[1] = (f16)xv.y;
  *(f16x2*)&xb[(size_t)wid * 128 + k] = o;

  float4 vs0 = *(const float4*)&V1s[k * 4];
  float4 vs1 = *(const float4*)&V1s[(k + 1) * 4];
  float4 vd0 = *(const float4*)&V1d[k * 4];
  float4 vd1 = *(const float4*)&V1d[(k + 1) * 4];
  float s[4], d[4];
  s[0] = xv.x * vs0.x + xv.y * vs1.x;
  s[1] = xv.x * vs0.y + xv.y * vs1.y;
  s[2] = xv.x * vs0.z + xv.y * vs1.z;
  s[3] = xv.x * vs0.w + xv.y * vs1.w;
  d[0] = xv.x * vd0.x + xv.y * vd1.x;
  d[1] = xv.x * vd0.y + xv.y * vd1.y;
  d[2] = xv.x * vd0.z + xv.y * vd1.z;
  d[3] = xv.x * vd0.w + xv.y * vd1.w;
#pragma unroll
  for (int h = 0; h < 4; ++h) {
#pragma unroll
    for (int off = 32; off; off >>= 1) {
      s[h] += __shfl_xor(s[h], off);
      d[h] += __shfl_xor(d[h], off);
    }
  }
  if (lane == 0) {
    *(float4*)&as1[(size_t)wid * 4] = make_float4(s[0], s[1], s[2], s[3]);
    *(float4*)&ad1[(size_t)wid * 4] = make_float4(d[0], d[1], d[2], d[3]);
  }
}

// W [R][C] f32 -> Wt [C][R] f16
__global__ __launch_bounds__(256) void cvt_w_t(const float* __restrict__ W,
                                               f16* __restrict__ Wt, int R, int C) {
  int idx = blockIdx.x * 256 + threadIdx.x;
  if (idx >= R * C) return;
  int cc = idx / R, rr = idx - cc * R;
  Wt[idx] = (f16)W[(size_t)rr * C + cc];
}

__global__ __launch_bounds__(256) void make_v1(const float* __restrict__ W1,
                                               const float* __restrict__ att_s,
                                               const float* __restrict__ att_d,
                                               float* __restrict__ V1s,
                                               float* __restrict__ V1d) {
  const int wid = (blockIdx.x * 256 + threadIdx.x) >> 6;  // 0..511
  const int lane = threadIdx.x & 63;
  const int k = wid >> 2, h = wid & 3;
  const float* wrow = W1 + (size_t)k * 512 + h * 128;
  float2 wv = *(const float2*)&wrow[lane * 2];
  float2 sv = *(const float2*)&att_s[h * 128 + lane * 2];
  float2 dv = *(const float2*)&att_d[h * 128 + lane * 2];
  float ps = wv.x * sv.x + wv.y * sv.y;
  float pd = wv.x * dv.x + wv.y * dv.y;
#pragma unroll
  for (int off = 32; off; off >>= 1) {
    ps += __shfl_xor(ps, off);
    pd += __shfl_xor(pd, off);
  }
  if (lane == 0) { V1s[k * 4 + h] = ps; V1d[k * 4 + h] = pd; }
}

__global__ __launch_bounds__(256) void make_v2(const float* __restrict__ W2,
                                               const float* __restrict__ att_s,
                                               const float* __restrict__ att_d,
                                               float* __restrict__ V2s,
                                               float* __restrict__ V2d) {
  const int wid = (blockIdx.x * 256 + threadIdx.x) >> 6;  // k = 0..511
  const int lane = threadIdx.x & 63;
  const float* wrow = W2 + (size_t)wid * 128;
  float2 wv = *(const float2*)&wrow[lane * 2];
  float2 sv = *(const float2*)&att_s[lane * 2];
  float2 dv = *(const float2*)&att_d[lane * 2];
  float ps = wv.x * sv.x + wv.y * sv.y;
  float pd = wv.x * dv.x + wv.y * dv.y;
#pragma unroll
  for (int off = 32; off; off >>= 1) {
    ps += __shfl_xor(ps, off);
    pd += __shfl_xor(pd, off);
  }
  if (lane == 0) { V2s[wid] = ps; V2d[wid] = pd; }
}

// ---------------------------------------------------------------------------
// MFMA GEMM (unchanged)
// ---------------------------------------------------------------------------
template <int K>
__global__ __launch_bounds__(256) void gemm_bt_f16(const f16* __restrict__ A,
                                                   const f16* __restrict__ Bt,
                                                   f16* __restrict__ C, int N) {
  constexpr int LDT = 40;
  __shared__ __align__(16) f16 As[128 * LDT];
  __shared__ __align__(16) f16 Bs[128 * LDT];
  const int tid = threadIdx.x;
  const int lane = tid & 63;
  const int g = lane >> 4, r16 = lane & 15;
  const int w = tid >> 6, wr = w >> 1, wc = w & 1;
  const long bm = (long)blockIdx.x * 128, bn = (long)blockIdx.y * 128;

  const int row0 = tid >> 2, h0 = tid & 3;
  const int p1 = (h0 & 1) * 16 + (h0 >> 1) * 4;
  const long ga0 = (bm + row0) * (long)K + h0 * 8;
  const long ga1 = (bm + row0 + 64) * (long)K + h0 * 8;
  const long gb0 = (bn + row0) * (long)K + h0 * 8;
  const long gb1 = (bn + row0 + 64) * (long)K + h0 * 8;
  const int la0 = row0 * LDT + p1, la1 = (row0 + 64) * LDT + p1;

  f32x4 acc[4][4] = {};

  for (int k0 = 0; k0 < K; k0 += 32) {
    __syncthreads();
    f16x8 va0 = *(const f16x8*)&A[ga0 + k0];
    f16x8 va1 = *(const f16x8*)&A[ga1 + k0];
    f16x8 vb0 = *(const f16x8*)&Bt[gb0 + k0];
    f16x8 vb1 = *(const f16x8*)&Bt[gb1 + k0];
    *(f16x4*)&As[la0]     = __builtin_shufflevector(va0, va0, 0, 1, 2, 3);
    *(f16x4*)&As[la0 + 8] = __builtin_shufflevector(va0, va0, 4, 5, 6, 7);
    *(f16x4*)&As[la1]     = __builtin_shufflevector(va1, va1, 0, 1, 2, 3);
    *(f16x4*)&As[la1 + 8] = __builtin_shufflevector(va1, va1, 4, 5, 6, 7);
    *(f16x4*)&Bs[la0]     = __builtin_shufflevector(vb0, vb0, 0, 1, 2, 3);
    *(f16x4*)&Bs[la0 + 8] = __builtin_shufflevector(vb0, vb0, 4, 5, 6, 7);
    *(f16x4*)&Bs[la1]     = __builtin_shufflevector(vb1, vb1, 0, 1, 2, 3);
    *(f16x4*)&Bs[la1 + 8] = __builtin_shufflevector(vb1, vb1, 4, 5, 6, 7);
    __syncthreads();
    f16x8 af[4], bfv[4];
#pragma unroll
    for (int m = 0; m < 4; ++m)
      af[m] = *(const f16x8*)&As[(wr * 64 + m * 16 + r16) * LDT + g * 8];
#pragma unroll
    for (int n = 0; n < 4; ++n)
      bfv[n] = *(const f16x8*)&Bs[(wc * 64 + n * 16 + r16) * LDT + g * 8];
#pragma unroll
    for (int m = 0; m < 4; ++m)
#pragma unroll
      for (int n = 0; n < 4; ++n)
        acc[m][n] = __builtin_amdgcn_mfma_f32_16x16x32_f16(af[m], bfv[n], acc[m][n], 0, 0, 0);
  }

#pragma unroll
  for (int m = 0; m < 4; ++m) {
#pragma unroll
    for (int n = 0; n < 4; ++n) {
      const long row = bm + wr * 64 + m * 16 + g * 4;
      const long col = bn + wc * 64 + n * 16 + r16;
#pragma unroll
      for (int r = 0; r < 4; ++r)
        C[(row + r) * N + col] = (f16)acc[m][n][r];
    }
  }
}

// ---------------------------------------------------------------------------
// layer-1 aggregation (H=4, D=128): single-pass no-max softmax
// (acc = sum exp(e)*h ; Z = sum exp(e) ; out = acc/Z), 4-deep pipelined gather.
// lane layout: hd = lane>>4 (head), col0 = lane*8 (8 f16 of the 512-wide row)
// ---------------------------------------------------------------------------
__global__ __launch_bounds__(256) void aggregate1(
    const f16* __restrict__ hsrc, const float* __restrict__ a_src,
    const float* __restrict__ a_dst, const int* __restrict__ rowstart,
    const int* __restrict__ csr, const float* __restrict__ bias,
    const float* __restrict__ V2s, const float* __restrict__ V2d,
    f16* __restrict__ outb, float* __restrict__ as2, float* __restrict__ ad2,
    int n) {
  const int wid0 = (blockIdx.x * blockDim.x + threadIdx.x) >> 6;
  if (wid0 >= n) return;
  const int wid = rfl(wid0);
  const int lane = threadIdx.x & 63;
  const int hd = lane >> 4;
  const int col0 = lane * 8;
  const int rs = rfl(rowstart[wid]);
  const int re = rfl(rowstart[wid + 1]);
  const float adh = a_dst[(size_t)wid * 4 + hd];

  constexpr int DEPTH = 4;
  float areg[DEPTH];
  f16x8 hreg[DEPTH];
  // prologue: issue DEPTH edge loads (dummy = first edge, never consumed OOB)
#pragma unroll
  for (int p = 0; p < DEPTH; ++p) {
    const int k = rs + p;
    const int s = csr[(k < re) ? k : rs];
    areg[p] = a_src[(size_t)s * 4 + hd];
    hreg[p] = *(const f16x8*)&hsrc[(size_t)s * 512 + col0];
  }

  float acc[8] = {};
  float Z = 0.f;
  for (int k = rs; k < re; k += DEPTH) {
#pragma unroll
    for (int p = 0; p < DEPTH; ++p) {
      const int cur = k + p;
      if (cur >= re) break;  // wave-uniform
      float e = areg[p] + adh;
      e = e > 0.f ? e : 0.2f * e;
      const float w = __expf(e);
      const f16x8 h = hreg[p];
      // refill slot p with edge cur+DEPTH
      const int nk = cur + DEPTH;
      if (nk < re) {
        const int s = csr[nk];
        areg[p] = a_src[(size_t)s * 4 + hd];
        hreg[p] = *(const f16x8*)&hsrc[(size_t)s * 512 + col0];
      }
      Z += w;
#pragma unroll
      for (int j = 0; j < 8; ++j) acc[j] += w * (float)h[j];
    }
  }
  const float inv = 1.f / (Z + 1e-16f);

  // epilogue: normalize, bias + ELU + f16 store; fused layer-2 attention dot
  float4 vsa = *(const float4*)&V2s[col0];
  float4 vsb = *(const float4*)&V2s[col0 + 4];
  float4 vda = *(const float4*)&V2d[col0];
  float4 vdb = *(const float4*)&V2d[col0 + 4];
  const float vs[8] = {vsa.x, vsa.y, vsa.z, vsa.w, vsb.x, vsb.y, vsb.z, vsb.w};
  const float vd[8] = {vda.x, vda.y, vda.z, vda.w, vdb.x, vdb.y, vdb.z, vdb.w};
  f16x8 o;
  float s2 = 0.f, d2 = 0.f;
#pragma unroll
  for (int j = 0; j < 8; ++j) {
    float v = acc[j] * inv + bias[col0 + j];
    v = v > 0.f ? v : (__expf(v) - 1.f);
    o[j] = (f16)v;
    s2 += v * vs[j];
    d2 += v * vd[j];
  }
  *(f16x8*)&outb[(size_t)wid * 512 + col0] = o;
#pragma unroll
  for (int off = 32; off; off >>= 1) {
    s2 += __shfl_xor(s2, off);
    d2 += __shfl_xor(d2, off);
  }
  if (lane == 0) { as2[wid] = s2; ad2[wid] = d2; }
}

// ---------------------------------------------------------------------------
// layer-2 aggregation (H=1, D=128): single-pass softmax, 8-deep pipeline,
// fused L2-normalize.  col0 = lane*2.
// ---------------------------------------------------------------------------
__global__ __launch_bounds__(256) void aggregate2(
    const f16* __restrict__ hsrc, const float* __restrict__ a_src,
    const float* __restrict__ a_dst, const int* __restrict__ rowstart,
    const int* __restrict__ csr, const float* __restrict__ bias,
    float* __restrict__ out, int n) {
  const int wid0 = (blockIdx.x * blockDim.x + threadIdx.x) >> 6;
  if (wid0 >= n) return;
  const int wid = rfl(wid0);
  const int lane = threadIdx.x & 63;
  const int col0 = lane * 2;
  const int rs = rfl(rowstart[wid]);
  const int re = rfl(rowstart[wid + 1]);
  const float ad = a_dst[wid];

  constexpr int DEPTH = 8;
  float areg[DEPTH];
  f16x2 hreg[DEPTH];
#pragma unroll
  for (int p = 0; p < DEPTH; ++p) {
    const int k = rs + p;
    const int s = csr[(k < re) ? k : rs];
    areg[p] = a_src[s];
    hreg[p] = *(const f16x2*)&hsrc[(size_t)s * 128 + col0];
  }

  float a0 = 0.f, a1 = 0.f, Z = 0.f;
  for (int k = rs; k < re; k += DEPTH) {
#pragma unroll
    for (int p = 0; p < DEPTH; ++p) {
      const int cur = k + p;
      if (cur >= re) break;  // wave-uniform
      float e = areg[p] + ad;
      e = e > 0.f ? e : 0.2f * e;
      const float w = __expf(e);
      const f16x2 h = hreg[p];
      const int nk = cur + DEPTH;
      if (nk < re) {
        const int s = csr[nk];
        areg[p] = a_src[s];
        hreg[p] = *(const f16x2*)&hsrc[(size_t)s * 128 + col0];
      }
      Z += w;
      a0 += w * (float)h[0];
      a1 += w * (float)h[1];
    }
  }
  const float inv = 1.f / (Z + 1e-16f);
  float v0 = a0 * inv + bias[col0], v1 = a1 * inv + bias[col0 + 1];
  v0 = v0 > 0.f ? v0 : (__expf(v0) - 1.f);
  v1 = v1 > 0.f ? v1 : (__expf(v1) - 1.f);
  float ss = v0 * v0 + v1 * v1;
#pragma unroll
  for (int off = 32; off; off >>= 1) ss += __shfl_xor(ss, off);
  const float invn = 1.f / fmaxf(sqrtf(ss), 1e-12f);
  float2 ov; ov.x = v0 * invn; ov.y = v1 * invn;
  *(float2*)&out[(size_t)wid * 128 + col0] = ov;
}

// ---------------------------------------------------------------------------
extern "C" void kernel_launch(void* const* d_in, const int* in_sizes, int n_in,
                              void* d_out, int out_size, void* d_ws, size_t ws_size,
                              hipStream_t stream) {
  const float* x        = (const float*)d_in[0];
  const int*   ei       = (const int*)d_in[1];
  const float* W1       = (const float*)d_in[2];
  const float* att_src1 = (const float*)d_in[3];
  const float* att_dst1 = (const float*)d_in[4];
  const float* bias1    = (const float*)d_in[5];
  const float* W2       = (const float*)d_in[6];
  const float* att_src2 = (const float*)d_in[7];
  const float* att_dst2 = (const float*)d_in[8];
  const float* bias2    = (const float*)d_in[9];
  float* out = (float*)d_out;

  char* ws = (char*)d_ws;
  size_t off = 0;
  auto alloc = [&](size_t bytes) {
    char* p = ws + off;
    off = (off + bytes + 255) & ~(size_t)255;
    return p;
  };
  f16* xb    = (f16*)alloc(sizeof(f16) * (size_t)M_PAD * 128);
  f16* w1t   = (f16*)alloc(sizeof(f16) * 512 * 128);
  f16* w2t   = (f16*)alloc(sizeof(f16) * 128 * 512);
  f16* h1b   = (f16*)alloc(sizeof(f16) * (size_t)M_PAD * 512);
  f16* out1b = (f16*)alloc(sizeof(f16) * (size_t)M_PAD * 512);
  float* V1s = (float*)alloc(sizeof(float) * 512);
  float* V1d = (float*)alloc(sizeof(float) * 512);
  float* V2s = (float*)alloc(sizeof(float) * 512);
  float* V2d = (float*)alloc(sizeof(float) * 512);
  float* as1 = (float*)alloc(sizeof(float) * N_NODES * 4);
  float* ad1 = (float*)alloc(sizeof(float) * N_NODES * 4);
  float* as2 = (float*)alloc(sizeof(float) * N_NODES);
  float* ad2 = (float*)alloc(sizeof(float) * N_NODES);
  int* rowstart = (int*)alloc(sizeof(int) * (SCAN_PAD + 4));
  int* cursor   = (int*)alloc(sizeof(int) * SCAN_PAD);
  int* bsum     = (int*)alloc(sizeof(int) * 64);
  int* csr      = (int*)alloc(sizeof(int) * TOT_EDGES);
  f16* h2b = h1b;  // alias: h1b dead after aggregate1

  const int wgrid = (N_NODES * 64) / 256;  // 12500 blocks, 1 wave/node

  // CSR build
  zero_int<<<(SCAN_PAD + 255) / 256, 256, 0, stream>>>(cursor, SCAN_PAD);
  count_kernel<<<(TOT_EDGES + 255) / 256, 256, 0, stream>>>(ei, cursor);
  block_scan<<<49, 256, 0, stream>>>(cursor, rowstart, bsum);
  bsum_scan<<<1, 64, 0, stream>>>(bsum, 49);
  add_off<<<49, 256, 0, stream>>>(rowstart, bsum, cursor);
  fill_kernel<<<(TOT_EDGES + 255) / 256, 256, 0, stream>>>(ei, cursor, csr);

  // weights + attention projection vectors
  make_v1<<<128, 256, 0, stream>>>(W1, att_src1, att_dst1, V1s, V1d);
  make_v2<<<128, 256, 0, stream>>>(W2, att_src2, att_dst2, V2s, V2d);
  cvt_w_t<<<(512 * 128 + 255) / 256, 256, 0, stream>>>(W1, w1t, 128, 512);
  cvt_w_t<<<(512 * 128 + 255) / 256, 256, 0, stream>>>(W2, w2t, 512, 128);
  prep_x<<<(M_PAD * 64) / 256, 256, 0, stream>>>(x, xb, V1s, V1d, as1, ad1);

  // layer 1
  gemm_bt_f16<128><<<dim3(M_PAD / 128, 4), 256, 0, stream>>>(xb, w1t, h1b, 512);
  aggregate1<<<wgrid, 256, 0, stream>>>(h1b, as1, ad1, rowstart, csr, bias1,
                                        V2s, V2d, out1b, as2, ad2, N_NODES);

  // layer 2
  gemm_bt_f16<512><<<dim3(M_PAD / 128, 1), 256, 0, stream>>>(out1b, w2t, h2b, 128);
  aggregate2<<<wgrid, 256, 0, stream>>>(h2b, as2, ad2, rowstart, csr, bias2, out, N_NODES);
}